// Round 6
// baseline (222.149 us; speedup 1.0000x reference)
//
#include <hip/hip_runtime.h>
#include <cmath>

#define NPTS 262144
#define NLVL 16
#define NDENSE 5
#define NHASH 11
#define HASH_MASK 0x7FFFFu

#define PPT 2                                  // points per thread in enc_hash
#define CHUNK (256 * PPT)                      // 512 points per block
#define CHUNKS_PER_LVL (NPTS / CHUNK)          // 512
#define TOTAL_UNITS (NHASH * CHUNKS_PER_LVL)   // 5632
#define UNITS_PER_XCD (TOTAL_UNITS / 8)        // 704

typedef float vf2 __attribute__((ext_vector_type(2)));
typedef float vf4 __attribute__((ext_vector_type(4)));

struct MetaD { float scale[NDENSE]; unsigned off[NDENSE]; unsigned res[NDENSE]; };
struct MetaH { float scale[NHASH]; unsigned off[NHASH]; };

// ---------------- hash level inner (hsize = 2^19, pow2 mask) ----------------
__device__ __forceinline__ vf2 hash_level(
    const float* __restrict__ emb, unsigned off, float s,
    float x, float y, float z)
{
    const float px = x * s, py = y * s, pz = z * s;
    const float gx = floorf(px), gy = floorf(py), gz = floorf(pz);
    const float fx = px - gx, fy = py - gy, fz = pz - gz;
    const unsigned ix = (unsigned)gx, iy = (unsigned)gy, iz = (unsigned)gz;

    const unsigned hy0 = iy * 2654435761u, hy1 = hy0 + 2654435761u;
    const unsigned hz0 = iz * 805459861u,  hz1 = hz0 + 805459861u;
    const unsigned hyz[4] = {hy0 ^ hz0, hy1 ^ hz0, hy0 ^ hz1, hy1 ^ hz1};

    const float wy0 = 1.0f - fy, wz0 = 1.0f - fz;
    const float wc[4] = {wy0 * wz0, fy * wz0, wy0 * fz, fy * fz};
    const float wx0 = 1.0f - fx;

    const vf2* __restrict__ emb2 = (const vf2*)emb;
    const vf4* __restrict__ emb4 = (const vf4*)emb;

    float a0 = 0.0f, a1 = 0.0f;
    if ((ix & 1u) == 0u) {
        // x-corners (ix, ix+1) hash to (i0, i0^1): one aligned float4 covers both
#pragma unroll
        for (int c = 0; c < 4; ++c) {
            const unsigned i0 = (ix ^ hyz[c]) & HASH_MASK;
            const vf4 f = emb4[(off + (i0 & ~1u)) >> 1];
            const bool sw = (i0 & 1u);
            const float c0x = sw ? f.z : f.x, c0y = sw ? f.w : f.y;
            const float c1x = sw ? f.x : f.z, c1y = sw ? f.y : f.w;
            a0 += wc[c] * (wx0 * c0x + fx * c1x);
            a1 += wc[c] * (wx0 * c0y + fx * c1y);
        }
    } else {
#pragma unroll
        for (int c = 0; c < 4; ++c) {
            const unsigned i0 = (ix        ^ hyz[c]) & HASH_MASK;
            const unsigned i1 = ((ix + 1u) ^ hyz[c]) & HASH_MASK;
            const vf2 f0 = emb2[off + i0];
            const vf2 f1 = emb2[off + i1];
            a0 += wc[c] * (wx0 * f0.x + fx * f1.x);
            a1 += wc[c] * (wx0 * f0.y + fx * f1.y);
        }
    }
    vf2 r; r.x = a0; r.y = a1;
    return r;
}

// hash levels 5..15, XCD-affine and exactly balanced:
// block b -> xcd = b&7 (HW round-robin), unit g = xcd*704 + (b>>3);
// level = g/512, chunk = g%512. Each XCD does 704 units, <=3 tables sequential.
__global__ __launch_bounds__(256) void enc_hash(
    const float* __restrict__ means, const float* __restrict__ emb,
    float* __restrict__ dst, int lvl_major, MetaH meta)
{
    const unsigned b   = blockIdx.x;
    const unsigned g   = (b & 7u) * UNITS_PER_XCD + (b >> 3);
    const unsigned il  = g >> 9;          // / CHUNKS_PER_LVL
    const unsigned chk = g & 511u;

    const float sc     = meta.scale[il];
    const unsigned off = meta.off[il];
    const unsigned lvl = il + NDENSE;

    const unsigned p0 = chk * CHUNK + threadIdx.x;
    vf2* __restrict__ dst2 = (vf2*)dst;

#pragma unroll
    for (int pp = 0; pp < PPT; ++pp) {
        const unsigned p = p0 + (unsigned)pp * 256u;
        const float x = (means[3 * p + 0] + 1.0f) * 0.5f;
        const float y = (means[3 * p + 1] + 1.0f) * 0.5f;
        const float z = (means[3 * p + 2] + 1.0f) * 0.5f;
        const vf2 a = hash_level(emb, off, sc, x, y, z);
        if (lvl_major) {
            // ws is stream-once: bypass L2 to protect table residency
            __builtin_nontemporal_store(a, &dst2[(size_t)il * NPTS + p]);
        } else {
            dst2[(size_t)p * NLVL + lvl] = a;
        }
    }
}

// ------- finalize: dense levels 0..4 inline + hash results from ws,
//         write full 128 B lines point-major (explicit vf4 regs, no arrays) -------
__global__ __launch_bounds__(256) void finalize(
    const float* __restrict__ means, const float* __restrict__ emb,
    const float* __restrict__ ws, float* __restrict__ out, MetaD meta)
{
    const int p = blockIdx.x * 256 + threadIdx.x;
    const vf2* __restrict__ ws2 = (const vf2*)ws;

    // issue the 11 coalesced ws reads first (independent, long latency)
    vf2 h0  = __builtin_nontemporal_load(&ws2[(size_t)0  * NPTS + p]);
    vf2 h1  = __builtin_nontemporal_load(&ws2[(size_t)1  * NPTS + p]);
    vf2 h2  = __builtin_nontemporal_load(&ws2[(size_t)2  * NPTS + p]);
    vf2 h3  = __builtin_nontemporal_load(&ws2[(size_t)3  * NPTS + p]);
    vf2 h4  = __builtin_nontemporal_load(&ws2[(size_t)4  * NPTS + p]);
    vf2 h5  = __builtin_nontemporal_load(&ws2[(size_t)5  * NPTS + p]);
    vf2 h6  = __builtin_nontemporal_load(&ws2[(size_t)6  * NPTS + p]);
    vf2 h7  = __builtin_nontemporal_load(&ws2[(size_t)7  * NPTS + p]);
    vf2 h8  = __builtin_nontemporal_load(&ws2[(size_t)8  * NPTS + p]);
    vf2 h9  = __builtin_nontemporal_load(&ws2[(size_t)9  * NPTS + p]);
    vf2 h10 = __builtin_nontemporal_load(&ws2[(size_t)10 * NPTS + p]);

    const float x = (means[3 * p + 0] + 1.0f) * 0.5f;
    const float y = (means[3 * p + 1] + 1.0f) * 0.5f;
    const float z = (means[3 * p + 2] + 1.0f) * 0.5f;

    const vf2* __restrict__ emb2 = (const vf2*)emb;

    vf2 d[NDENSE];
#pragma unroll
    for (int l = 0; l < NDENSE; ++l) {
        const float s      = meta.scale[l];
        const unsigned off = meta.off[l];
        const unsigned r   = meta.res[l];

        const float px = x * s, py = y * s, pz = z * s;
        const float gx = floorf(px), gy = floorf(py), gz = floorf(pz);
        const float fx = px - gx, fy = py - gy, fz = pz - gz;
        const unsigned ix = (unsigned)gx, iy = (unsigned)gy, iz = (unsigned)gz;

        const unsigned base = ix + iy * r + iz * r * r + off;
        const unsigned dy = r, dz = r * r;

        vf2 f[8];
        f[0] = emb2[base];           f[1] = emb2[base + 1];
        f[2] = emb2[base + dy];      f[3] = emb2[base + dy + 1];
        f[4] = emb2[base + dz];      f[5] = emb2[base + dz + 1];
        f[6] = emb2[base + dz + dy]; f[7] = emb2[base + dz + dy + 1];

        const float wx0 = 1.0f - fx, wy0 = 1.0f - fy, wz0 = 1.0f - fz;
        const float w00 = wz0 * wy0, w01 = wz0 * fy, w10 = fz * wy0, w11 = fz * fy;
        d[l].x = w00 * (wx0 * f[0].x + fx * f[1].x) + w01 * (wx0 * f[2].x + fx * f[3].x)
               + w10 * (wx0 * f[4].x + fx * f[5].x) + w11 * (wx0 * f[6].x + fx * f[7].x);
        d[l].y = w00 * (wx0 * f[0].y + fx * f[1].y) + w01 * (wx0 * f[2].y + fx * f[3].y)
               + w10 * (wx0 * f[4].y + fx * f[5].y) + w11 * (wx0 * f[6].y + fx * f[7].y);
    }

    float* o = out + (size_t)p * (2 * NLVL);
    vf4 v;
    v.x = d[0].x; v.y = d[0].y; v.z = d[1].x; v.w = d[1].y;
    __builtin_nontemporal_store(v, (vf4*)(o + 0));
    v.x = d[2].x; v.y = d[2].y; v.z = d[3].x; v.w = d[3].y;
    __builtin_nontemporal_store(v, (vf4*)(o + 4));
    v.x = d[4].x; v.y = d[4].y; v.z = h0.x;  v.w = h0.y;
    __builtin_nontemporal_store(v, (vf4*)(o + 8));
    v.x = h1.x; v.y = h1.y; v.z = h2.x; v.w = h2.y;
    __builtin_nontemporal_store(v, (vf4*)(o + 12));
    v.x = h3.x; v.y = h3.y; v.z = h4.x; v.w = h4.y;
    __builtin_nontemporal_store(v, (vf4*)(o + 16));
    v.x = h5.x; v.y = h5.y; v.z = h6.x; v.w = h6.y;
    __builtin_nontemporal_store(v, (vf4*)(o + 20));
    v.x = h7.x; v.y = h7.y; v.z = h8.x; v.w = h8.y;
    __builtin_nontemporal_store(v, (vf4*)(o + 24));
    v.x = h9.x; v.y = h9.y; v.z = h10.x; v.w = h10.y;
    __builtin_nontemporal_store(v, (vf4*)(o + 28));
}

// fallback dense kernel (only if ws too small for staging)
__global__ __launch_bounds__(256) void enc_dense_direct(
    const float* __restrict__ means, const float* __restrict__ emb,
    float* __restrict__ dst, MetaD meta)
{
    const int p = blockIdx.x * 256 + threadIdx.x;
    const int l = blockIdx.y;

    const float x = (means[3 * p + 0] + 1.0f) * 0.5f;
    const float y = (means[3 * p + 1] + 1.0f) * 0.5f;
    const float z = (means[3 * p + 2] + 1.0f) * 0.5f;

    const float s      = meta.scale[l];
    const unsigned off = meta.off[l];
    const unsigned r   = meta.res[l];

    const float px = x * s, py = y * s, pz = z * s;
    const float gx = floorf(px), gy = floorf(py), gz = floorf(pz);
    const float fx = px - gx, fy = py - gy, fz = pz - gz;
    const unsigned ix = (unsigned)gx, iy = (unsigned)gy, iz = (unsigned)gz;

    const unsigned base = ix + iy * r + iz * r * r + off;
    const unsigned dy = r, dz = r * r;

    const vf2* __restrict__ emb2 = (const vf2*)emb;
    vf2 f[8];
    f[0] = emb2[base];           f[1] = emb2[base + 1];
    f[2] = emb2[base + dy];      f[3] = emb2[base + dy + 1];
    f[4] = emb2[base + dz];      f[5] = emb2[base + dz + 1];
    f[6] = emb2[base + dz + dy]; f[7] = emb2[base + dz + dy + 1];

    const float wx0 = 1.0f - fx, wy0 = 1.0f - fy, wz0 = 1.0f - fz;
    const float w00 = wz0 * wy0, w01 = wz0 * fy, w10 = fz * wy0, w11 = fz * fy;
    vf2 a;
    a.x = w00 * (wx0 * f[0].x + fx * f[1].x) + w01 * (wx0 * f[2].x + fx * f[3].x)
        + w10 * (wx0 * f[4].x + fx * f[5].x) + w11 * (wx0 * f[6].x + fx * f[7].x);
    a.y = w00 * (wx0 * f[0].y + fx * f[1].y) + w01 * (wx0 * f[2].y + fx * f[3].y)
        + w10 * (wx0 * f[4].y + fx * f[5].y) + w11 * (wx0 * f[6].y + fx * f[7].y);

    ((vf2*)dst)[(size_t)p * NLVL + l] = a;
}

extern "C" void kernel_launch(void* const* d_in, const int* in_sizes, int n_in,
                              void* d_out, int out_size, void* d_ws, size_t ws_size,
                              hipStream_t stream)
{
    const float* means = (const float*)d_in[0];
    const float* emb   = (const float*)d_in[1];
    float* out         = (float*)d_out;

    MetaD md;
    MetaH mh;
    const double lg = log2(1.38191288);
    unsigned off = 0;
    for (int l = 0; l < NLVL; ++l) {
        const double scale_d = pow(2.0, (double)l * lg) * 16.0 - 1.0;
        const unsigned res_enc = (unsigned)ceil(scale_d) + 1u;

        const double gres_d = ceil(16.0 * pow(1.38191288, (double)l));
        unsigned long long r3 = (unsigned long long)gres_d;
        r3 = r3 * r3 * r3;
        unsigned long long pl = r3 < (1ull << 19) ? r3 : (1ull << 19);
        pl = (pl + 7ull) / 8ull * 8ull;

        if (l < NDENSE) {
            md.scale[l] = (float)scale_d;
            md.off[l]   = off;
            md.res[l]   = res_enc;
        } else {
            mh.scale[l - NDENSE] = (float)scale_d;
            mh.off[l - NDENSE]   = off;
        }
        off += (unsigned)pl;
    }

    const size_t ws_needed = (size_t)NHASH * NPTS * sizeof(vf2);  // 23 MB
    if (ws_size >= ws_needed) {
        float* ws = (float*)d_ws;
        enc_hash<<<TOTAL_UNITS, 256, 0, stream>>>(means, emb, ws, 1, mh);
        finalize<<<NPTS / 256, 256, 0, stream>>>(means, emb, ws, out, md);
    } else {
        enc_hash<<<TOTAL_UNITS, 256, 0, stream>>>(means, emb, out, 0, mh);
        enc_dense_direct<<<dim3(NPTS / 256, NDENSE, 1), 256, 0, stream>>>(means, emb, out, md);
    }
}